// Round 5
// baseline (419.722 us; speedup 1.0000x reference)
//
#include <hip/hip_runtime.h>
#include <hip/hip_bf16.h>

// Problem constants: x[4,512,64,64], 32 groups, attention over 4096 spatial positions.
constexpr int BATCH = 4;
constexpr int CH    = 512;     // channels
constexpr int HWN   = 4096;    // h*w
constexpr int NG    = 32;      // groups
constexpr float SM_SCALE = 0.044194173824159216f; // 512^-0.5
constexpr float SM_L2E   = 0.06376608440f;        // SM_SCALE * log2(e)

// ---------------- static device workspace ----------------
__device__ __align__(256) ushort g_ht[(long)BATCH*HWN*CH];   // h_t[b][n][c]
__device__ __align__(256) ushort g_qt[(long)BATCH*HWN*CH];   // q_t[b][n][o]
__device__ __align__(256) ushort g_kt[(long)BATCH*HWN*CH];   // k_t[b][m][o]
__device__ __align__(256) ushort g_v [(long)BATCH*CH*HWN];   // v[b][c][m]
__device__ __align__(256) ushort g_S [(long)BATCH*HWN*HWN];  // P_raw[b][n][m] (128 MiB)
__device__ __align__(256) ushort g_ot[(long)BATCH*HWN*CH];   // O_raw_t[b][n][c]
__device__ __align__(256) ushort g_wq[CH*CH], g_wk[CH*CH], g_wv[CH*CH], g_wp[CH*CH];
__device__ float g_mean[BATCH*NG], g_rstd[BATCH*NG];
__device__ float g_rowsum[BATCH*HWN];

typedef short v8s __attribute__((ext_vector_type(8)));
typedef float f32x4 __attribute__((ext_vector_type(4)));

__device__ inline ushort f2b(float f){
  __hip_bfloat16 h = __float2bfloat16(f);
  return __builtin_bit_cast(ushort, h);
}

__device__ inline void gload16(const ushort* g, ushort* lds_base){
  __builtin_amdgcn_global_load_lds(
      (const __attribute__((address_space(1))) unsigned int*)g,
      (__attribute__((address_space(3))) unsigned int*)lds_base, 16, 0, 0);
}

__device__ inline void blockbar(){
  asm volatile("" ::: "memory");
  __builtin_amdgcn_s_barrier();
  asm volatile("" ::: "memory");
}

// ---------------- weights fp32 -> bf16 + rowsum zero-init -------------------------
__global__ __launch_bounds__(256) void prep_weights(const float* wq, const float* wk,
                                                    const float* wv, const float* wp){
  int t = blockIdx.x*256 + threadIdx.x;
  g_wq[t] = f2b(wq[t]);
  g_wk[t] = f2b(wk[t]);
  g_wv[t] = f2b(wv[t]);
  g_wp[t] = f2b(wp[t]);
  if (t < BATCH*HWN) g_rowsum[t] = 0.0f;
}

// ---------------- GroupNorm stats ----------------
__global__ __launch_bounds__(256) void gn_stats(const float* x){
  __shared__ float ss[4], ss2[4];
  const float4* p = (const float4*)(x + (long)blockIdx.x*65536);
  float s = 0.f, s2 = 0.f;
  for (int i = threadIdx.x; i < 16384; i += 256){
    float4 v = p[i];
    s  += v.x + v.y + v.z + v.w;
    s2 += v.x*v.x + v.y*v.y + v.z*v.z + v.w*v.w;
  }
  for (int off = 1; off < 64; off <<= 1){
    s  += __shfl_xor(s,  off);
    s2 += __shfl_xor(s2, off);
  }
  if ((threadIdx.x & 63) == 0){ ss[threadIdx.x>>6] = s; ss2[threadIdx.x>>6] = s2; }
  __syncthreads();
  if (threadIdx.x == 0){
    float S1 = ss[0]+ss[1]+ss[2]+ss[3], S2 = ss2[0]+ss2[1]+ss2[2]+ss2[3];
    float mean = S1 * (1.0f/65536.0f);
    float var  = S2 * (1.0f/65536.0f) - mean*mean;
    g_mean[blockIdx.x] = mean;
    g_rstd[blockIdx.x] = rsqrtf(var + 1e-6f);
  }
}

// ---------------- GroupNorm apply + transpose ----------------
__global__ __launch_bounds__(256) void gn_apply(const float* x, const float* gamma, const float* beta){
  __shared__ ushort tile[64][72];
  const int b = blockIdx.z, tc = blockIdx.y, tn = blockIdx.x;
  const int t = threadIdx.x;
  const int r = t >> 4;
  const int ncol = (t & 15) * 4;
  const float* xb = x + ((long)b*CH + tc*64)*HWN + tn*64;
  #pragma unroll
  for (int rg = 0; rg < 4; rg++){
    int c_local = rg*16 + r;
    int c = tc*64 + c_local;
    int gidx = b*NG + (c >> 4);
    float mean = g_mean[gidx], rstd = g_rstd[gidx];
    float ga = gamma[c], be = beta[c];
    float4 v = *(const float4*)(xb + (long)c_local*HWN + ncol);
    tile[c_local][ncol+0] = f2b((v.x - mean)*rstd*ga + be);
    tile[c_local][ncol+1] = f2b((v.y - mean)*rstd*ga + be);
    tile[c_local][ncol+2] = f2b((v.z - mean)*rstd*ga + be);
    tile[c_local][ncol+3] = f2b((v.w - mean)*rstd*ga + be);
  }
  __syncthreads();
  ushort* ht = g_ht + ((long)b*HWN + tn*64)*CH + tc*64;
  #pragma unroll
  for (int rg = 0; rg < 4; rg++){
    int n_local = rg*16 + r;
    int cl = (t & 15) * 4;
    ushort4 pk;
    pk.x = tile[cl+0][n_local];
    pk.y = tile[cl+1][n_local];
    pk.z = tile[cl+2][n_local];
    pk.w = tile[cl+3][n_local];
    *(ushort4*)(ht + (long)n_local*CH + cl) = pk;
  }
}

// ---------------- 128^2 m97-style GEMM for the small matmuls ----------------
// CFG: 0=Q  1=K  2=V  5=proj
template<int CFG>
__global__ __launch_bounds__(256, 2) void gemm_bt(const float* bias, const float* xres, float* outf){
  constexpr int Kdim = CH;
  constexpr int BIAS = (CFG==0 || CFG==1) ? 2 : (CFG==2) ? 1 : 0;

  __shared__ __align__(16) ushort As[128*32];
  __shared__ __align__(16) ushort Bs[128*32];

  const int z = blockIdx.z;
  const int tm = blockIdx.x, tn = blockIdx.y;
  const int t = threadIdx.x;

  const ushort *Ap, *Bp;  ushort* Cp = nullptr;
  int lda, ldb, ldc = 0;
  if constexpr (CFG==0){ Ap=g_ht+(long)z*HWN*CH; Bp=g_wq; Cp=g_qt+(long)z*HWN*CH; lda=CH;  ldb=CH;  ldc=CH;  }
  if constexpr (CFG==1){ Ap=g_ht+(long)z*HWN*CH; Bp=g_wk; Cp=g_kt+(long)z*HWN*CH; lda=CH;  ldb=CH;  ldc=CH;  }
  if constexpr (CFG==2){ Ap=g_wv; Bp=g_ht+(long)z*HWN*CH; Cp=g_v +(long)z*CH*HWN; lda=CH;  ldb=CH;  ldc=HWN; }
  if constexpr (CFG==5){ Ap=g_ot+(long)z*HWN*CH; Bp=g_wp; lda=CH; ldb=CH; }

  const int lane = t & 63, wid = t >> 6;
  const int wr = (wid >> 1) * 64, wc = (wid & 1) * 64;
  const int lr = lane & 15, lk = lane >> 4;

  const int srow = t >> 2, sko = t & 3;
  const int wave_base = (t & 192) * 8;

  f32x4 acc[4][4] = {};

  for (int kt = 0; kt < Kdim; kt += 32){
    __syncthreads();
    #pragma unroll
    for (int i = 0; i < 2; i++){
      int row = srow + i*64;
      const ushort* ga = Ap + (long)(tm*128 + row)*lda + kt + sko*8;
      const ushort* gb = Bp + (long)(tn*128 + row)*ldb + kt + sko*8;
      gload16(ga, As + wave_base + i*256*8);
      gload16(gb, Bs + wave_base + i*256*8);
    }
    __syncthreads();
    v8s af[4], bfr[4];
    #pragma unroll
    for (int mi = 0; mi < 4; mi++){
      int row = wr + mi*16 + lr;
      af[mi] = *(const v8s*)(As + row*32 + lk*8);
    }
    #pragma unroll
    for (int ni = 0; ni < 4; ni++){
      int row = wc + ni*16 + lr;
      bfr[ni] = *(const v8s*)(Bs + row*32 + lk*8);
    }
    #pragma unroll
    for (int mi = 0; mi < 4; mi++)
      #pragma unroll
      for (int ni = 0; ni < 4; ni++)
        acc[mi][ni] = __builtin_amdgcn_mfma_f32_16x16x32_bf16(af[mi], bfr[ni], acc[mi][ni], 0, 0, 0);
  }

  if constexpr (CFG==5){
    float* ob = outf + (long)z*CH*HWN;
    const float* xb = xres + (long)z*CH*HWN;
    #pragma unroll
    for (int mi = 0; mi < 4; mi++){
      #pragma unroll
      for (int ni = 0; ni < 4; ni++){
        int col = tn*128 + wc + ni*16 + lr;        // o
        int rowm = tm*128 + wr + mi*16 + lk*4;     // n
        float cb = bias[col];
        long off = (long)col*HWN + rowm;
        float4 xv = *(const float4*)(xb + off);
        float4 ov;
        ov.x = acc[mi][ni][0] + cb + xv.x;
        ov.y = acc[mi][ni][1] + cb + xv.y;
        ov.z = acc[mi][ni][2] + cb + xv.z;
        ov.w = acc[mi][ni][3] + cb + xv.w;
        *(float4*)(ob + off) = ov;
      }
    }
  } else {
    #pragma unroll
    for (int mi = 0; mi < 4; mi++){
      #pragma unroll
      for (int ni = 0; ni < 4; ni++){
        int col = tn*128 + wc + ni*16 + lr;
        float cb = 0.f;
        if constexpr (BIAS==2) cb = bias[col];
        #pragma unroll
        for (int j = 0; j < 4; j++){
          int rowm = tm*128 + wr + mi*16 + lk*4 + j;
          float v = acc[mi][ni][j];
          if constexpr (BIAS==1) v += bias[rowm]; else v += cb;
          Cp[(long)rowm*ldc + col] = f2b(v);
        }
      }
    }
  }
}

// ---------------- 8-phase counted-vmcnt 256-wide GEMM (T3+T4+T5+swizzle) ----------
// CFG=3: S = q_t * k_t^T -> P_raw=exp(S*scale) + rowsum.  BM=256 BN=256, K=512.
// CFG=4: O_t = P_raw * v^T, /rowsum.                      BM=256 BN=128, K=4096.
// LDS layout in 16B units: [dbuf][A-half0|A-half1|B-half0|B-half1]; within a half,
// unit = rowInHalf*8 + slot; slot holds global c16 = slot ^ (rowInHalf&7)  (3-bit
// XOR involution within each 64-unit wave-load window -> conflict-free ds_read_b128
// while global fetch of a row-octet stays one contiguous 128B segment).
// Schedule per iteration (K-tiles X=2i even->dbuf0, Y=X+1 odd->dbuf1), one s_barrier
// per phase, stage-slot is dead >=1 phase before its overwrite, vmcnt only at ph4/ph8:
//   ph1: stage A1(Y)   ; read A0(X),B0(X) ; MFMA Q1(X)
//   ph2: stage B1(Y)   ; read A1(X)       ; MFMA Q2(X)
//   ph3: stage B0(X+2) ; read B1(X),A0(X) ; MFMA Q3(X)
//   ph4: stage A0(X+2) ; read A1(X)       ; MFMA Q4(X) ; vmcnt(La+Lb)
//   ph5: stage A1(X+2) ; read A0(Y),B0(Y) ; MFMA Q1(Y)
//   ph6: stage B1(X+2) ; read A1(Y)       ; MFMA Q2(Y)
//   ph7: stage B0(Y+2) ; read B1(Y),A0(Y) ; MFMA Q3(Y)
//   ph8: stage A0(Y+2) ; read A1(Y)       ; MFMA Q4(Y) ; vmcnt(La+Lb)
// In-order vmem retirement => vmcnt(La+Lb) leaves exactly the 2 newest halves in
// flight; every half is guaranteed landed >= 1 phase before first read (verified
// case-by-case, incl. prologue handoff). Last iteration: skip ph3..ph8 stages,
// vmcnt(0) at ph4.
template<int CFG>
__global__ __launch_bounds__(512, 2) void gemm256(){
  constexpr int Kdim = (CFG==4) ? HWN : CH;
  constexpr int BN   = (CFG==3) ? 256 : 128;
  constexpr int NI   = BN/64;          // acc frags per wave in N (4 or 2)
  constexpr int NI2  = NI/2;
  constexpr int AUNITS = 2048;         // 256 rows x 8 units
  constexpr int BUNITS = BN*64/8;
  constexpr int BH   = BUNITS/2;       // units per B-half
  constexpr int BBIT = (CFG==3) ? 5 : 4;
  constexpr int Lb   = BH/512;         // B loads/thread/half (2 or 1); A = 2
  constexpr int DBUF = AUNITS + BUNITS;
  constexpr int NT = Kdim/64, NITER = NT/2;

  __shared__ __align__(16) ushort lds[DBUF*2*8];

  const int t = threadIdx.x, lane = t & 63, wid = t >> 6;
  const int wm = wid >> 2, wn = wid & 3;
  const int lr = lane & 15, lk = lane >> 4;
  const int tm = blockIdx.x, tn = blockIdx.y, z = blockIdx.z;

  const ushort *Ap, *Bp; ushort* Cp; long lda, ldb, ldc;
  if constexpr (CFG==3){
    Ap = g_qt + (long)z*HWN*CH; lda = CH;
    Bp = g_kt + (long)z*HWN*CH; ldb = CH;
    Cp = g_S  + (long)z*HWN*HWN; ldc = HWN;
  } else {
    Ap = g_S  + (long)z*HWN*HWN; lda = HWN;
    Bp = g_v  + (long)z*CH*HWN;  ldb = HWN;
    Cp = g_ot + (long)z*HWN*CH;  ldc = CH;
  }

  const int srw  = lane >> 3;            // row-in-octet 0..7
  const int sc16 = (lane & 7) ^ srw;     // swizzled global fetch column
  const int rxor = lr & 7;               // read-side xor

  auto stageA = [&](int h, int T){
    #pragma unroll
    for (int j = 0; j < 2; j++){
      int W = wid*2 + j;                 // 16 windows of 64 units
      int RH = W*8 + srw;                // 0..127
      int r = (RH>>6)*128 + h*64 + (RH&63);
      gload16(Ap + (long)(tm*256 + r)*lda + T*64 + sc16*8,
              lds + ((T&1)*DBUF + h*1024 + W*64)*8);
    }
  };
  auto stageB = [&](int h, int T){
    #pragma unroll
    for (int j = 0; j < Lb; j++){
      int W = wid*Lb + j;
      int RH = W*8 + srw;
      int r = (RH>>BBIT)*(2<<BBIT) + h*(1<<BBIT) + (RH & ((1<<BBIT)-1));
      gload16(Bp + (long)(tn*BN + r)*ldb + T*64 + sc16*8,
              lds + ((T&1)*DBUF + AUNITS + h*BH + W*64)*8);
    }
  };
  auto readA = [&](int d, int h, v8s (&a)[4][2]){
    #pragma unroll
    for (int mp = 0; mp < 4; mp++){
      int RH = wm*64 + mp*16 + lr;
      #pragma unroll
      for (int kk = 0; kk < 2; kk++){
        int u = d*DBUF + h*1024 + RH*8 + ((kk*4 + lk) ^ rxor);
        a[mp][kk] = *(const v8s*)(lds + u*8);
      }
    }
  };
  auto readB = [&](int d, int h, v8s (&b)[NI2][2]){
    #pragma unroll
    for (int np = 0; np < NI2; np++){
      int RH = (CFG==3) ? (wn*32 + np*16 + lr) : (wn*16 + lr);
      #pragma unroll
      for (int kk = 0; kk < 2; kk++){
        int u = d*DBUF + AUNITS + h*BH + RH*8 + ((kk*4 + lk) ^ rxor);
        b[np][kk] = *(const v8s*)(lds + u*8);
      }
    }
  };

  f32x4 acc[8][NI] = {};
  auto mm = [&](const v8s (&a)[4][2], const v8s (&b)[NI2][2], int mh, int nh){
    __builtin_amdgcn_s_setprio(1);
    #pragma unroll
    for (int mp = 0; mp < 4; mp++)
      #pragma unroll
      for (int np = 0; np < NI2; np++)
        #pragma unroll
        for (int kk = 0; kk < 2; kk++)
          acc[mh*4+mp][nh*NI2+np] = __builtin_amdgcn_mfma_f32_16x16x32_bf16(
              a[mp][kk], b[np][kk], acc[mh*4+mp][nh*NI2+np], 0, 0, 0);
    __builtin_amdgcn_s_setprio(0);
  };

  #define VM_STEADY() do { if constexpr (CFG==3) asm volatile("s_waitcnt vmcnt(4)" ::: "memory"); \
                           else                  asm volatile("s_waitcnt vmcnt(3)" ::: "memory"); } while(0)
  #define VM_DRAIN()  asm volatile("s_waitcnt vmcnt(0)" ::: "memory")

  // prologue: tile0 fully + first halves of tile1
  stageA(0, 0); stageB(0, 0); stageA(1, 0); stageB(1, 0); stageA(0, 1); stageB(0, 1);
  VM_STEADY();
  blockbar();

  for (int it = 0; it < NITER; ++it){
    const int X = 2*it, Y = X + 1;
    const bool last = (it == NITER-1);
    v8s a[4][2], b[NI2][2];

    // ph1
    stageA(1, Y);
    readA(0, 0, a); readB(0, 0, b);
    mm(a, b, 0, 0);
    blockbar();
    // ph2
    stageB(1, Y);
    readA(0, 1, a);
    mm(a, b, 1, 0);
    blockbar();
    // ph3
    if (!last) stageB(0, X+2);
    readB(0, 1, b); readA(0, 0, a);
    mm(a, b, 0, 1);
    blockbar();
    // ph4
    if (!last) stageA(0, X+2);
    readA(0, 1, a);
    mm(a, b, 1, 1);
    if (last) VM_DRAIN(); else VM_STEADY();
    blockbar();
    // ph5
    if (!last) stageA(1, X+2);
    readA(1, 0, a); readB(1, 0, b);
    mm(a, b, 0, 0);
    blockbar();
    // ph6
    if (!last) stageB(1, X+2);
    readA(1, 1, a);
    mm(a, b, 1, 0);
    blockbar();
    // ph7
    if (!last) stageB(0, Y+2);
    readB(1, 1, b); readA(1, 0, a);
    mm(a, b, 0, 1);
    blockbar();
    // ph8
    if (!last) stageA(0, Y+2);
    readA(1, 1, a);
    mm(a, b, 1, 1);
    if (!last) VM_STEADY();
    blockbar();
  }
  #undef VM_STEADY
  #undef VM_DRAIN

  if constexpr (CFG==3){
    // epilogue: P = exp(S*scale), store bf16, accumulate row sums
    float rs[8][4] = {};
    #pragma unroll
    for (int mi = 0; mi < 8; mi++){
      #pragma unroll
      for (int ni = 0; ni < NI; ni++){
        int col = tn*256 + wn*64 + ni*16 + lr;
        #pragma unroll
        for (int j = 0; j < 4; j++){
          float p = exp2f(acc[mi][ni][j] * SM_L2E);
          int row = tm*256 + wm*128 + mi*16 + lk*4 + j;
          Cp[(long)row*ldc + col] = f2b(p);
          rs[mi][j] += p;
        }
      }
    }
    float* rsum = g_rowsum + (long)z*HWN;
    #pragma unroll
    for (int mi = 0; mi < 8; mi++){
      #pragma unroll
      for (int j = 0; j < 4; j++){
        float s = rs[mi][j];
        s += __shfl_xor(s, 1); s += __shfl_xor(s, 2);
        s += __shfl_xor(s, 4); s += __shfl_xor(s, 8);
        if (lr == 0)
          atomicAdd(&rsum[tm*256 + wm*128 + mi*16 + lk*4 + j], s);
      }
    }
  } else {
    const float* rsum = g_rowsum + (long)z*HWN;
    #pragma unroll
    for (int mi = 0; mi < 8; mi++){
      int rowb = tm*256 + wm*128 + mi*16 + lk*4;
      float4 s4 = *(const float4*)(rsum + rowb);
      float inv[4] = {1.0f/s4.x, 1.0f/s4.y, 1.0f/s4.z, 1.0f/s4.w};
      #pragma unroll
      for (int ni = 0; ni < NI; ni++){
        int col = tn*BN + wn*32 + ni*16 + lr;
        #pragma unroll
        for (int j = 0; j < 4; j++)
          Cp[(long)(rowb + j)*ldc + col] = f2b(acc[mi][ni][j] * inv[j]);
      }
    }
  }
}

extern "C" void kernel_launch(void* const* d_in, const int* in_sizes, int n_in,
                              void* d_out, int out_size, void* d_ws, size_t ws_size,
                              hipStream_t stream){
  const float* x     = (const float*)d_in[0];
  const float* gamma = (const float*)d_in[1];
  const float* beta  = (const float*)d_in[2];
  const float* wq    = (const float*)d_in[3];
  const float* bq    = (const float*)d_in[4];
  const float* wk    = (const float*)d_in[5];
  const float* bk    = (const float*)d_in[6];
  const float* wv    = (const float*)d_in[7];
  const float* bv    = (const float*)d_in[8];
  const float* wp    = (const float*)d_in[9];
  const float* bp    = (const float*)d_in[10];
  float* out = (float*)d_out;

  prep_weights<<<1024, 256, 0, stream>>>(wq, wk, wv, wp);
  gn_stats<<<BATCH*NG, 256, 0, stream>>>(x);
  gn_apply<<<dim3(HWN/64, CH/64, BATCH), 256, 0, stream>>>(x, gamma, beta);

  gemm_bt<0><<<dim3(HWN/128, CH/128, BATCH), 256, 0, stream>>>(bq, nullptr, nullptr);  // q_t
  gemm_bt<1><<<dim3(HWN/128, CH/128, BATCH), 256, 0, stream>>>(bk, nullptr, nullptr);  // k_t
  gemm_bt<2><<<dim3(CH/128, HWN/128, BATCH), 256, 0, stream>>>(bv, nullptr, nullptr);  // v
  gemm256<3><<<dim3(HWN/256, HWN/256, BATCH), 512, 0, stream>>>();                     // P_raw + rowsum
  gemm256<4><<<dim3(HWN/256, CH/128, BATCH), 512, 0, stream>>>();                      // O_t (/rowsum)
  gemm_bt<5><<<dim3(HWN/128, CH/128, BATCH), 256, 0, stream>>>(bp, x, out);            // out
}

// Round 6
// 378.837 us; speedup vs baseline: 1.1079x; 1.1079x over previous
//
#include <hip/hip_runtime.h>
#include <hip/hip_bf16.h>

// Problem constants: x[4,512,64,64], 32 groups, attention over 4096 spatial positions.
constexpr int BATCH = 4;
constexpr int CH    = 512;     // channels
constexpr int HWN   = 4096;    // h*w
constexpr int NG    = 32;      // groups
constexpr float SM_SCALE = 0.044194173824159216f; // 512^-0.5
constexpr float SM_L2E   = 0.06376608440f;        // SM_SCALE * log2(e)

// ---------------- static device workspace ----------------
__device__ __align__(256) ushort g_ht[(long)BATCH*HWN*CH];    // h_t[b][n][c]
__device__ __align__(256) ushort g_qk[(long)BATCH*HWN*1024];  // [b][n][0:512=q | 512:1024=k]
__device__ __align__(256) ushort g_v [(long)BATCH*CH*HWN];    // v[b][c][m]
__device__ __align__(256) ushort g_S [(long)BATCH*HWN*HWN];   // P_raw[b][n][m] (128 MiB)
__device__ __align__(256) ushort g_ot[(long)BATCH*HWN*CH];    // O_raw_t[b][n][c]
__device__ __align__(256) ushort g_wqk[2*CH*CH];              // rows 0..511=wq, 512..1023=wk
__device__ __align__(256) ushort g_wv[CH*CH], g_wp[CH*CH];
__device__ float g_bqk[2*CH];
__device__ float g_mean[BATCH*NG], g_rstd[BATCH*NG];
__device__ float g_rowsum[BATCH*HWN];

typedef short v8s __attribute__((ext_vector_type(8)));
typedef float f32x4 __attribute__((ext_vector_type(4)));

__device__ inline ushort f2b(float f){
  __hip_bfloat16 h = __float2bfloat16(f);
  return __builtin_bit_cast(ushort, h);
}

__device__ inline void gload16(const ushort* g, ushort* lds_base){
  __builtin_amdgcn_global_load_lds(
      (const __attribute__((address_space(1))) unsigned int*)g,
      (__attribute__((address_space(3))) unsigned int*)lds_base, 16, 0, 0);
}

__device__ inline void blockbar(){
  asm volatile("" ::: "memory");
  __builtin_amdgcn_s_barrier();
  asm volatile("" ::: "memory");
}

// ---------------- weight prep: wq|wk -> g_wqk, wv, wp; bias concat; rowsum=0 -----
__global__ __launch_bounds__(256) void prep_weights(const float* wq, const float* wk,
                                                    const float* wv, const float* wp,
                                                    const float* bq, const float* bk){
  int t = blockIdx.x*256 + threadIdx.x;   // < 262144
  g_wqk[t]        = f2b(wq[t]);
  g_wqk[CH*CH+t]  = f2b(wk[t]);
  g_wv[t] = f2b(wv[t]);
  g_wp[t] = f2b(wp[t]);
  if (t < BATCH*HWN) g_rowsum[t] = 0.0f;
  if (t < 2*CH) g_bqk[t] = (t < CH) ? bq[t] : bk[t-CH];
}

// ---------------- GroupNorm stats ----------------
__global__ __launch_bounds__(256) void gn_stats(const float* x){
  __shared__ float ss[4], ss2[4];
  const float4* p = (const float4*)(x + (long)blockIdx.x*65536);
  float s = 0.f, s2 = 0.f;
  for (int i = threadIdx.x; i < 16384; i += 256){
    float4 v = p[i];
    s  += v.x + v.y + v.z + v.w;
    s2 += v.x*v.x + v.y*v.y + v.z*v.z + v.w*v.w;
  }
  for (int off = 1; off < 64; off <<= 1){
    s  += __shfl_xor(s,  off);
    s2 += __shfl_xor(s2, off);
  }
  if ((threadIdx.x & 63) == 0){ ss[threadIdx.x>>6] = s; ss2[threadIdx.x>>6] = s2; }
  __syncthreads();
  if (threadIdx.x == 0){
    float S1 = ss[0]+ss[1]+ss[2]+ss[3], S2 = ss2[0]+ss2[1]+ss2[2]+ss2[3];
    float mean = S1 * (1.0f/65536.0f);
    float var  = S2 * (1.0f/65536.0f) - mean*mean;
    g_mean[blockIdx.x] = mean;
    g_rstd[blockIdx.x] = rsqrtf(var + 1e-6f);
  }
}

// ---------------- GroupNorm apply + transpose ----------------
__global__ __launch_bounds__(256) void gn_apply(const float* x, const float* gamma, const float* beta){
  __shared__ ushort tile[64][72];
  const int b = blockIdx.z, tc = blockIdx.y, tn = blockIdx.x;
  const int t = threadIdx.x;
  const int r = t >> 4;
  const int ncol = (t & 15) * 4;
  const float* xb = x + ((long)b*CH + tc*64)*HWN + tn*64;
  #pragma unroll
  for (int rg = 0; rg < 4; rg++){
    int c_local = rg*16 + r;
    int c = tc*64 + c_local;
    int gidx = b*NG + (c >> 4);
    float mean = g_mean[gidx], rstd = g_rstd[gidx];
    float ga = gamma[c], be = beta[c];
    float4 v = *(const float4*)(xb + (long)c_local*HWN + ncol);
    tile[c_local][ncol+0] = f2b((v.x - mean)*rstd*ga + be);
    tile[c_local][ncol+1] = f2b((v.y - mean)*rstd*ga + be);
    tile[c_local][ncol+2] = f2b((v.z - mean)*rstd*ga + be);
    tile[c_local][ncol+3] = f2b((v.w - mean)*rstd*ga + be);
  }
  __syncthreads();
  ushort* ht = g_ht + ((long)b*HWN + tn*64)*CH + tc*64;
  #pragma unroll
  for (int rg = 0; rg < 4; rg++){
    int n_local = rg*16 + r;
    int cl = (t & 15) * 4;
    ushort4 pk;
    pk.x = tile[cl+0][n_local];
    pk.y = tile[cl+1][n_local];
    pk.z = tile[cl+2][n_local];
    pk.w = tile[cl+3][n_local];
    *(ushort4*)(ht + (long)n_local*CH + cl) = pk;
  }
}

// ---------------- 128^2 m97-style 2-phase GEMM ----------------
// CFG: 0=QK fused (A=h_t, Bt=wqk -> g_qk[n][1024], col bias g_bqk)
//      2=V        (A=wv, Bt=h_t -> v[c][m], row bias bv)
//      3=S        (A=g_qk q-half, Bt=g_qk k-half -> P_raw=exp(S*scale), rowsum atomics)
//      5=proj     (A=O_t, Bt=wp; out = x + c^T + bp)
// NOTE: __launch_bounds__(256,2) — (256,4) capped VGPR at 64 and regressed 20% (r3).
template<int CFG>
__global__ __launch_bounds__(256, 2) void gemm_bt(const float* bias, const float* xres, float* outf){
  constexpr int Kdim = CH;

  __shared__ __align__(16) ushort As[128*32];
  __shared__ __align__(16) ushort Bs[128*32];

  const int z = blockIdx.z;
  const int tm = blockIdx.x, tn = blockIdx.y;
  const int t = threadIdx.x;

  const ushort *Ap, *Bp;  ushort* Cp = nullptr;
  long lda, ldb, ldc = 0;
  if constexpr (CFG==0){ Ap=g_ht+(long)z*HWN*CH; Bp=g_wqk; Cp=g_qk+(long)z*HWN*1024; lda=CH; ldb=CH; ldc=1024; }
  if constexpr (CFG==2){ Ap=g_wv; Bp=g_ht+(long)z*HWN*CH; Cp=g_v +(long)z*CH*HWN; lda=CH; ldb=CH; ldc=HWN; }
  if constexpr (CFG==3){ Ap=g_qk+(long)z*HWN*1024; Bp=Ap+512; Cp=g_S+(long)z*HWN*HWN; lda=1024; ldb=1024; ldc=HWN; }
  if constexpr (CFG==5){ Ap=g_ot+(long)z*HWN*CH; Bp=g_wp; lda=CH; ldb=CH; }

  const int lane = t & 63, wid = t >> 6;
  const int wr = (wid >> 1) * 64, wc = (wid & 1) * 64;
  const int lr = lane & 15, lk = lane >> 4;

  const int srow = t >> 2, sko = t & 3;
  const int wave_base = (t & 192) * 8;

  f32x4 acc[4][4] = {};

  for (int kt = 0; kt < Kdim; kt += 32){
    __syncthreads();
    #pragma unroll
    for (int i = 0; i < 2; i++){
      int row = srow + i*64;
      const ushort* ga = Ap + (long)(tm*128 + row)*lda + kt + sko*8;
      const ushort* gb = Bp + (long)(tn*128 + row)*ldb + kt + sko*8;
      gload16(ga, As + wave_base + i*256*8);
      gload16(gb, Bs + wave_base + i*256*8);
    }
    __syncthreads();
    v8s af[4], bfr[4];
    #pragma unroll
    for (int mi = 0; mi < 4; mi++){
      int row = wr + mi*16 + lr;
      af[mi] = *(const v8s*)(As + row*32 + lk*8);
    }
    #pragma unroll
    for (int ni = 0; ni < 4; ni++){
      int row = wc + ni*16 + lr;
      bfr[ni] = *(const v8s*)(Bs + row*32 + lk*8);
    }
    #pragma unroll
    for (int mi = 0; mi < 4; mi++)
      #pragma unroll
      for (int ni = 0; ni < 4; ni++)
        acc[mi][ni] = __builtin_amdgcn_mfma_f32_16x16x32_bf16(af[mi], bfr[ni], acc[mi][ni], 0, 0, 0);
  }

  if constexpr (CFG==3){
    // P = exp(S*scale) (no max-sub: |S|max ~1.2 by construction), bf16 store + rowsum
    float rs[4][4] = {};
    #pragma unroll
    for (int mi = 0; mi < 4; mi++){
      #pragma unroll
      for (int ni = 0; ni < 4; ni++){
        int col = tn*128 + wc + ni*16 + lr;
        #pragma unroll
        for (int j = 0; j < 4; j++){
          float p = exp2f(acc[mi][ni][j] * SM_L2E);
          int rowm = tm*128 + wr + mi*16 + lk*4 + j;
          Cp[(long)rowm*ldc + col] = f2b(p);
          rs[mi][j] += p;
        }
      }
    }
    #pragma unroll
    for (int mi = 0; mi < 4; mi++)
      #pragma unroll
      for (int j = 0; j < 4; j++){
        float s = rs[mi][j];
        s += __shfl_xor(s, 1); s += __shfl_xor(s, 2);
        s += __shfl_xor(s, 4); s += __shfl_xor(s, 8);
        rs[mi][j] = s;
      }
    if (lr == 0){
      float* rsum = g_rowsum + (long)z*HWN;
      #pragma unroll
      for (int mi = 0; mi < 4; mi++)
        #pragma unroll
        for (int j = 0; j < 4; j++)
          atomicAdd(&rsum[tm*128 + wr + mi*16 + lk*4 + j], rs[mi][j]);
    }
  } else if constexpr (CFG==5){
    float* ob = outf + (long)z*CH*HWN;
    const float* xb = xres + (long)z*CH*HWN;
    #pragma unroll
    for (int mi = 0; mi < 4; mi++){
      #pragma unroll
      for (int ni = 0; ni < 4; ni++){
        int col = tn*128 + wc + ni*16 + lr;        // o
        int rowm = tm*128 + wr + mi*16 + lk*4;     // n
        float cb = bias[col];
        long off = (long)col*HWN + rowm;
        float4 xv = *(const float4*)(xb + off);
        float4 ov;
        ov.x = acc[mi][ni][0] + cb + xv.x;
        ov.y = acc[mi][ni][1] + cb + xv.y;
        ov.z = acc[mi][ni][2] + cb + xv.z;
        ov.w = acc[mi][ni][3] + cb + xv.w;
        *(float4*)(ob + off) = ov;
      }
    }
  } else {
    #pragma unroll
    for (int mi = 0; mi < 4; mi++){
      #pragma unroll
      for (int ni = 0; ni < 4; ni++){
        int col = tn*128 + wc + ni*16 + lr;
        float cb = 0.f;
        if constexpr (CFG==0) cb = g_bqk[col];
        #pragma unroll
        for (int j = 0; j < 4; j++){
          int rowm = tm*128 + wr + mi*16 + lk*4 + j;
          float v = acc[mi][ni][j];
          if constexpr (CFG==2) v += bias[rowm]; else v += cb;
          Cp[(long)rowm*ldc + col] = f2b(v);
        }
      }
    }
  }
}

// ---------------- 8-phase counted-vmcnt 256-wide GEMM — long-K only (PV) ----------
// r5 measured: helps K=4096 (~81 µs, bank-conflict 0), hurts K=512 (prologue/drain
// dominates at NITER=4). Instantiated only for CFG=4.
// CFG=4: O_t = P_raw * v^T, /rowsum. BM=256 BN=128, K=4096.
template<int CFG>
__global__ __launch_bounds__(512, 2) void gemm256(){
  constexpr int Kdim = (CFG==4) ? HWN : CH;
  constexpr int BN   = (CFG==3) ? 256 : 128;
  constexpr int NI   = BN/64;
  constexpr int NI2  = NI/2;
  constexpr int AUNITS = 2048;
  constexpr int BUNITS = BN*64/8;
  constexpr int BH   = BUNITS/2;
  constexpr int BBIT = (CFG==3) ? 5 : 4;
  constexpr int Lb   = BH/512;
  constexpr int DBUF = AUNITS + BUNITS;
  constexpr int NT = Kdim/64, NITER = NT/2;

  __shared__ __align__(16) ushort lds[DBUF*2*8];

  const int t = threadIdx.x, lane = t & 63, wid = t >> 6;
  const int wm = wid >> 2, wn = wid & 3;
  const int lr = lane & 15, lk = lane >> 4;
  const int tm = blockIdx.x, tn = blockIdx.y, z = blockIdx.z;

  const ushort *Ap, *Bp; ushort* Cp; long lda, ldb, ldc;
  {
    Ap = g_S  + (long)z*HWN*HWN; lda = HWN;
    Bp = g_v  + (long)z*CH*HWN;  ldb = HWN;
    Cp = g_ot + (long)z*HWN*CH;  ldc = CH;
  }

  const int srw  = lane >> 3;
  const int sc16 = (lane & 7) ^ srw;
  const int rxor = lr & 7;

  auto stageA = [&](int h, int T){
    #pragma unroll
    for (int j = 0; j < 2; j++){
      int W = wid*2 + j;
      int RH = W*8 + srw;
      int r = (RH>>6)*128 + h*64 + (RH&63);
      gload16(Ap + (long)(tm*256 + r)*lda + T*64 + sc16*8,
              lds + ((T&1)*DBUF + h*1024 + W*64)*8);
    }
  };
  auto stageB = [&](int h, int T){
    #pragma unroll
    for (int j = 0; j < Lb; j++){
      int W = wid*Lb + j;
      int RH = W*8 + srw;
      int r = (RH>>BBIT)*(2<<BBIT) + h*(1<<BBIT) + (RH & ((1<<BBIT)-1));
      gload16(Bp + (long)(tn*BN + r)*ldb + T*64 + sc16*8,
              lds + ((T&1)*DBUF + AUNITS + h*BH + W*64)*8);
    }
  };
  auto readA = [&](int d, int h, v8s (&a)[4][2]){
    #pragma unroll
    for (int mp = 0; mp < 4; mp++){
      int RH = wm*64 + mp*16 + lr;
      #pragma unroll
      for (int kk = 0; kk < 2; kk++){
        int u = d*DBUF + h*1024 + RH*8 + ((kk*4 + lk) ^ rxor);
        a[mp][kk] = *(const v8s*)(lds + u*8);
      }
    }
  };
  auto readB = [&](int d, int h, v8s (&b)[NI2][2]){
    #pragma unroll
    for (int np = 0; np < NI2; np++){
      int RH = (CFG==3) ? (wn*32 + np*16 + lr) : (wn*16 + lr);
      #pragma unroll
      for (int kk = 0; kk < 2; kk++){
        int u = d*DBUF + AUNITS + h*BH + RH*8 + ((kk*4 + lk) ^ rxor);
        b[np][kk] = *(const v8s*)(lds + u*8);
      }
    }
  };

  f32x4 acc[8][NI] = {};
  auto mm = [&](const v8s (&a)[4][2], const v8s (&b)[NI2][2], int mh, int nh){
    __builtin_amdgcn_s_setprio(1);
    #pragma unroll
    for (int mp = 0; mp < 4; mp++)
      #pragma unroll
      for (int np = 0; np < NI2; np++)
        #pragma unroll
        for (int kk = 0; kk < 2; kk++)
          acc[mh*4+mp][nh*NI2+np] = __builtin_amdgcn_mfma_f32_16x16x32_bf16(
              a[mp][kk], b[np][kk], acc[mh*4+mp][nh*NI2+np], 0, 0, 0);
    __builtin_amdgcn_s_setprio(0);
  };

  #define VM_STEADY() asm volatile("s_waitcnt vmcnt(3)" ::: "memory")
  #define VM_DRAIN()  asm volatile("s_waitcnt vmcnt(0)" ::: "memory")

  stageA(0, 0); stageB(0, 0); stageA(1, 0); stageB(1, 0); stageA(0, 1); stageB(0, 1);
  VM_STEADY();
  blockbar();

  for (int it = 0; it < NITER; ++it){
    const int X = 2*it, Y = X + 1;
    const bool last = (it == NITER-1);
    v8s a[4][2], b[NI2][2];

    stageA(1, Y);
    readA(0, 0, a); readB(0, 0, b);
    mm(a, b, 0, 0);
    blockbar();
    stageB(1, Y);
    readA(0, 1, a);
    mm(a, b, 1, 0);
    blockbar();
    if (!last) stageB(0, X+2);
    readB(0, 1, b); readA(0, 0, a);
    mm(a, b, 0, 1);
    blockbar();
    if (!last) stageA(0, X+2);
    readA(0, 1, a);
    mm(a, b, 1, 1);
    if (last) VM_DRAIN(); else VM_STEADY();
    blockbar();
    if (!last) stageA(1, X+2);
    readA(1, 0, a); readB(1, 0, b);
    mm(a, b, 0, 0);
    blockbar();
    if (!last) stageB(1, X+2);
    readA(1, 1, a);
    mm(a, b, 1, 0);
    blockbar();
    if (!last) stageB(0, Y+2);
    readB(1, 1, b); readA(1, 0, a);
    mm(a, b, 0, 1);
    blockbar();
    if (!last) stageA(0, Y+2);
    readA(1, 1, a);
    mm(a, b, 1, 1);
    if (!last) VM_STEADY();
    blockbar();
  }
  #undef VM_STEADY
  #undef VM_DRAIN

  {
    const float* rsum = g_rowsum + (long)z*HWN;
    #pragma unroll
    for (int mi = 0; mi < 8; mi++){
      int rowb = tm*256 + wm*128 + mi*16 + lk*4;
      float4 s4 = *(const float4*)(rsum + rowb);
      float inv[4] = {1.0f/s4.x, 1.0f/s4.y, 1.0f/s4.z, 1.0f/s4.w};
      #pragma unroll
      for (int ni = 0; ni < NI; ni++){
        int col = tn*BN + wn*32 + ni*16 + lr;
        #pragma unroll
        for (int j = 0; j < 4; j++)
          Cp[(long)(rowb + j)*ldc + col] = f2b(acc[mi][ni][j] * inv[j]);
      }
    }
  }
}

extern "C" void kernel_launch(void* const* d_in, const int* in_sizes, int n_in,
                              void* d_out, int out_size, void* d_ws, size_t ws_size,
                              hipStream_t stream){
  const float* x     = (const float*)d_in[0];
  const float* gamma = (const float*)d_in[1];
  const float* beta  = (const float*)d_in[2];
  const float* wq    = (const float*)d_in[3];
  const float* bq    = (const float*)d_in[4];
  const float* wk    = (const float*)d_in[5];
  const float* bk    = (const float*)d_in[6];
  const float* wv    = (const float*)d_in[7];
  const float* bv    = (const float*)d_in[8];
  const float* wp    = (const float*)d_in[9];
  const float* bp    = (const float*)d_in[10];
  float* out = (float*)d_out;

  prep_weights<<<1024, 256, 0, stream>>>(wq, wk, wv, wp, bq, bk);
  gn_stats<<<BATCH*NG, 256, 0, stream>>>(x);
  gn_apply<<<dim3(HWN/64, CH/64, BATCH), 256, 0, stream>>>(x, gamma, beta);

  gemm_bt<0><<<dim3(HWN/128, 1024/128, BATCH), 256, 0, stream>>>(nullptr, nullptr, nullptr); // q|k fused
  gemm_bt<2><<<dim3(CH/128, HWN/128, BATCH), 256, 0, stream>>>(bv, nullptr, nullptr);        // v
  gemm_bt<3><<<dim3(HWN/128, HWN/128, BATCH), 256, 0, stream>>>(nullptr, nullptr, nullptr);  // P_raw + rowsum
  gemm256<4><<<dim3(HWN/256, CH/128, BATCH), 512, 0, stream>>>();                            // O_t (/rowsum)
  gemm_bt<5><<<dim3(HWN/128, CH/128, BATCH), 256, 0, stream>>>(bp, x, out);                  // out
}